// Round 1
// baseline (141.048 us; speedup 1.0000x reference)
//
#include <hip/hip_runtime.h>

// out[r,d] = x0[r,d] * dot(x_cross[r,:], w) + b[d] + x_cross[r,d]
// B=16384 rows, D=4096 cols, all fp32. Memory-bound: 768 MiB min traffic.

constexpr int D_DIM = 4096;
constexpr int TPB   = 256;          // threads per block
constexpr int V4    = D_DIM / 4;    // 1024 float4 per row
constexpr int F4PT  = V4 / TPB;     // 4 float4 per thread (16 floats)

__global__ __launch_bounds__(TPB)
void cross_fused_kernel(const float* __restrict__ x0,
                        const float* __restrict__ xc,
                        const float* __restrict__ w,
                        const float* __restrict__ bias,
                        float* __restrict__ out) {
    const int row = blockIdx.x;
    const size_t base = (size_t)row * D_DIM;

    const float4* __restrict__ xc4  = (const float4*)(xc + base);
    const float4* __restrict__ x04  = (const float4*)(x0 + base);
    const float4* __restrict__ w4   = (const float4*)w;
    const float4* __restrict__ b4   = (const float4*)bias;
    float4* __restrict__       out4 = (float4*)(out + base);

    const int t = threadIdx.x;

    // Phase 1: load x_cross slice into registers + partial dot with w.
    float4 xcv[F4PT];
    float partial = 0.0f;
#pragma unroll
    for (int i = 0; i < F4PT; ++i) {
        const int idx = t + i * TPB;          // coalesced: lane-contiguous float4
        xcv[i] = xc4[idx];
        const float4 wv = w4[idx];            // 16 KiB, L1/L2-resident
        partial += xcv[i].x * wv.x + xcv[i].y * wv.y
                 + xcv[i].z * wv.z + xcv[i].w * wv.w;
    }

    // Wave-64 shuffle reduction.
#pragma unroll
    for (int off = 32; off >= 1; off >>= 1)
        partial += __shfl_down(partial, off);

    // Cross-wave (4 waves) reduce via LDS, broadcast s to all threads.
    __shared__ float wsum[TPB / 64];
    const int lane = t & 63, wid = t >> 6;
    if (lane == 0) wsum[wid] = partial;
    __syncthreads();
    const float s = wsum[0] + wsum[1] + wsum[2] + wsum[3];

    // Phase 2: elementwise epilogue; x_cross slice already in registers.
#pragma unroll
    for (int i = 0; i < F4PT; ++i) {
        const int idx = t + i * TPB;
        const float4 x0v = x04[idx];
        const float4 bv  = b4[idx];           // 16 KiB, L1/L2-resident
        float4 o;
        o.x = x0v.x * s + bv.x + xcv[i].x;
        o.y = x0v.y * s + bv.y + xcv[i].y;
        o.z = x0v.z * s + bv.z + xcv[i].z;
        o.w = x0v.w * s + bv.w + xcv[i].w;
        out4[idx] = o;
    }
}

extern "C" void kernel_launch(void* const* d_in, const int* in_sizes, int n_in,
                              void* d_out, int out_size, void* d_ws, size_t ws_size,
                              hipStream_t stream) {
    const float* x0   = (const float*)d_in[0];
    const float* xc   = (const float*)d_in[1];
    const float* w    = (const float*)d_in[2];
    const float* bias = (const float*)d_in[3];
    float* out        = (float*)d_out;

    const int rows = in_sizes[0] / D_DIM;     // 16384
    cross_fused_kernel<<<rows, TPB, 0, stream>>>(x0, xc, w, bias, out);
}

// Round 3
// 138.606 us; speedup vs baseline: 1.0176x; 1.0176x over previous
//
#include <hip/hip_runtime.h>

// out[r,d] = x0[r,d] * dot(x_cross[r,:], w) + b[d] + x_cross[r,d]
// B=16384 rows, D=4096 cols, all fp32. Memory-bound: 768 MiB logical traffic.
//
// R3 = R2 with native ext_vector float4 (HIP_vector_type float4 is a class —
// __builtin_nontemporal_store rejects it; native vector is accepted).
//  - Prefetch BOTH x0 and x_cross into registers BEFORE the block reduction.
//  - Nontemporal stores for `out` (streaming, zero reuse) to keep the 256 MiB
//    Infinity Cache available for the inputs across graph replays.

typedef float f32x4 __attribute__((ext_vector_type(4)));

constexpr int D_DIM = 4096;
constexpr int TPB   = 256;          // threads per block
constexpr int V4    = D_DIM / 4;    // 1024 float4 per row
constexpr int F4PT  = V4 / TPB;     // 4 float4 per thread (16 floats)

__global__ __launch_bounds__(TPB)
void cross_fused_kernel(const float* __restrict__ x0,
                        const float* __restrict__ xc,
                        const float* __restrict__ w,
                        const float* __restrict__ bias,
                        float* __restrict__ out) {
    const int row = blockIdx.x;
    const size_t base = (size_t)row * D_DIM;

    const f32x4* __restrict__ xc4  = (const f32x4*)(xc + base);
    const f32x4* __restrict__ x04  = (const f32x4*)(x0 + base);
    const f32x4* __restrict__ w4   = (const f32x4*)w;
    const f32x4* __restrict__ b4   = (const f32x4*)bias;
    f32x4* __restrict__       out4 = (f32x4*)(out + base);

    const int t = threadIdx.x;

    // Phase 1: issue ALL global loads up front (xc + x0), dot xc·w.
    f32x4 xcv[F4PT];
    f32x4 x0v[F4PT];
#pragma unroll
    for (int i = 0; i < F4PT; ++i) {
        const int idx = t + i * TPB;          // coalesced: lane-contiguous float4
        xcv[i] = xc4[idx];
        x0v[i] = x04[idx];
    }

    float partial = 0.0f;
#pragma unroll
    for (int i = 0; i < F4PT; ++i) {
        const int idx = t + i * TPB;
        const f32x4 wv = w4[idx];             // 16 KiB, L2-resident
        partial += xcv[i].x * wv.x + xcv[i].y * wv.y
                 + xcv[i].z * wv.z + xcv[i].w * wv.w;
    }

    // Wave-64 shuffle reduction.
#pragma unroll
    for (int off = 32; off >= 1; off >>= 1)
        partial += __shfl_down(partial, off);

    // Cross-wave (4 waves) reduce via LDS, broadcast s to all threads.
    __shared__ float wsum[TPB / 64];
    const int lane = t & 63, wid = t >> 6;
    if (lane == 0) wsum[wid] = partial;
    __syncthreads();
    const float s = wsum[0] + wsum[1] + wsum[2] + wsum[3];

    // Phase 2: pure compute + streaming store (no further HBM reads except b).
#pragma unroll
    for (int i = 0; i < F4PT; ++i) {
        const int idx = t + i * TPB;
        const f32x4 bv = b4[idx];             // 16 KiB, L2-resident
        f32x4 o;
        o.x = fmaf(x0v[i].x, s, bv.x + xcv[i].x);
        o.y = fmaf(x0v[i].y, s, bv.y + xcv[i].y);
        o.z = fmaf(x0v[i].z, s, bv.z + xcv[i].z);
        o.w = fmaf(x0v[i].w, s, bv.w + xcv[i].w);
        __builtin_nontemporal_store(o, &out4[idx]);
    }
}

extern "C" void kernel_launch(void* const* d_in, const int* in_sizes, int n_in,
                              void* d_out, int out_size, void* d_ws, size_t ws_size,
                              hipStream_t stream) {
    const float* x0   = (const float*)d_in[0];
    const float* xc   = (const float*)d_in[1];
    const float* w    = (const float*)d_in[2];
    const float* bias = (const float*)d_in[3];
    float* out        = (float*)d_out;

    const int rows = in_sizes[0] / D_DIM;     // 16384
    cross_fused_kernel<<<rows, TPB, 0, stream>>>(x0, xc, w, bias, out);
}